// Round 14
// baseline (1597.664 us; speedup 1.0000x reference)
//
#include <hip/hip_runtime.h>
#include <hip/hip_cooperative_groups.h>
#include <stdint.h>

namespace cg = cooperative_groups;

// ---- problem constants ----
#define NB   32
#define NCH  128
#define IMG  64
#define IMG2 4096
#define OH   57
#define OHW  3249
#define CHW  415872
#define KTOP 256
#define NATT 17
#define NS   32
#define SCAP 512
#define NCAP 1536
#define NBUCK 8192
#define HSHIFT 18
#define TGT  512
#define RSTRIDE 72
#define BMW  12996
#define NBLK 256
#define NTHR 1024

typedef unsigned long long ull;

struct LdsResid { float Rs[IMG2]; uint32_t sidx[KTOP]; float sval[KTOP]; };
struct LdsConv  { float Rs[71 * 72]; uint32_t hl[NBUCK]; };
struct LdsThresh{ uint32_t buf[2][256]; };
struct LdsSuppg { uint32_t bm[BMW]; ull ck[NCAP]; float cg_l[NCAP]; };
struct LdsAtt   { float Wlds[NCH * 64]; float recon[64 * RSTRIDE];
                  ull kA[KTOP]; ull kB[KTOP]; float s_v[KTOP]; uint32_t s_pk[KTOP]; };
union LdsU { LdsResid r; LdsConv c; LdsThresh t; LdsSuppg s; LdsAtt a; };

__global__ __launch_bounds__(NTHR) void k_mega(
    const float* __restrict__ Y, const float* __restrict__ W, float* __restrict__ g,
    float* __restrict__ Rg, uint32_t* __restrict__ hist, uint32_t* __restrict__ thr,
    int* __restrict__ cand_cnt, uint32_t* __restrict__ cand_idx, float* __restrict__ cand_g,
    uint32_t* __restrict__ ns_idx, float* __restrict__ ns_g, uint32_t* __restrict__ ns_pk,
    float* __restrict__ sup_g, uint32_t* __restrict__ sup_pk,
    uint32_t* __restrict__ support_idx, float* __restrict__ support_val,
    uint32_t* __restrict__ sel_idx, float* __restrict__ sel_val,
    double* __restrict__ errg, double* __restrict__ l2buf)
{
    cg::grid_group grid = cg::this_grid();
    int blk = blockIdx.x, tid = threadIdx.x;
    int lane = tid & 63, wid = tid >> 6;

    __shared__ LdsU u;
    __shared__ double redd[16];
    __shared__ double esum[NATT + 1];
    __shared__ int sel_sh;
    __shared__ int cnts[NS];
    __shared__ int nns_sh;

    for (int t = 0; t < 3; ++t) {
        double* l2_out  = l2buf + (t % 2) * NB;
        double* l2_prev = l2buf + ((t + 1) % 2) * NB;
        grid.sync();   // entry / prev round's att+err complete

        // ===== phase 1: (update if t>0) + residual (blocks 0..31); zero hist/cand (32..255)
        if (blk < NB) {
            int b = blk;
            int n = 0;
            if (t > 0) {
                if (tid < NATT) {
                    double e = 0.0;
                    for (int b2 = 0; b2 < NB; ++b2) e += errg[tid * NB + b2];
                    esum[tid] = e;
                } else if (tid == NATT) {
                    double l2 = 0.0;
                    for (int b2 = 0; b2 < NB; ++b2) l2 += l2_prev[b2];
                    esum[NATT] = l2;
                }
                __syncthreads();
                if (tid == 0) {
                    double l2 = esum[NATT];
                    int sel = NATT - 1;
                    for (int a2 = 0; a2 < NATT; ++a2) if (esum[a2] < l2) { sel = a2; break; }
                    sel_sh = sel;
                }
                __syncthreads();
                int a = sel_sh;
                if (tid < KTOP) {
                    size_t o = ((size_t)a * NB + b) * KTOP + tid;
                    uint32_t ii = sel_idx[o];
                    float vv = sel_val[o];
                    u.r.sidx[tid] = ii; u.r.sval[tid] = vv;
                    support_idx[b * KTOP + tid] = ii;
                    support_val[b * KTOP + tid] = vv;
                }
                n = KTOP;
            }
            __syncthreads();
            ((float4*)u.r.Rs)[tid] = ((const float4*)(Y + b * IMG2))[tid];
            __syncthreads();
            for (int task = tid; task < n * 64; task += NTHR) {
                int i = task >> 6, tap = task & 63, p = tap >> 3, q = tap & 7;
                uint32_t idx = u.r.sidx[i];
                float val = u.r.sval[i];
                int c = idx / OHW, rem = idx % OHW, s = rem / OH, tt = rem % OH;
                atomicAdd(&u.r.Rs[(s + p) * IMG + (tt + q)], -val * W[c * 64 + p * 8 + q]);
            }
            __syncthreads();
            double acc = 0.0;
            for (int i = tid; i < IMG2; i += NTHR) {
                float v = u.r.Rs[i];
                Rg[b * IMG2 + i] = v;
                acc += (double)v * (double)v;
            }
            for (int d = 32; d > 0; d >>= 1) acc += __shfl_xor(acc, d, 64);
            if (lane == 0) redd[wid] = acc;
            __syncthreads();
            if (tid == 0) {
                double e = 0.0;
#pragma unroll
                for (int w2 = 0; w2 < 16; ++w2) e += redd[w2];
                l2_out[b] = e;
            }
        } else {
            int idx = (blk - NB) * NTHR + tid;     // zero hist (65536 uint4) + cand_cnt (256 uint4)
            if (idx < NB * NBUCK / 4) ((uint4*)hist)[idx] = make_uint4(0u, 0u, 0u, 0u);
            else if (idx < NB * NBUCK / 4 + NB * NS / 4)
                ((uint4*)cand_cnt)[idx - NB * NBUCK / 4] = make_uint4(0u, 0u, 0u, 0u);
        }
        grid.sync();

        // ===== phase 2: conv — 512 units (b, cg0), 8 channels each, 2 units/block
        for (int unit = blk; unit < NB * 16; unit += NBLK) {
            int b = unit >> 4, cg0 = unit & 15;
            for (int i = tid; i < 71 * 72; i += NTHR) u.c.Rs[i] = 0.f;
            for (int i = tid; i < NBUCK; i += NTHR) u.c.hl[i] = 0u;
            __syncthreads();
            {
                int row = tid >> 4, col4 = (tid & 15) * 4;
                *(float4*)&u.c.Rs[row * 72 + col4] = ((const float4*)(Rg + b * IMG2))[tid];
            }
            __syncthreads();
            int csub = tid >> 7;                 // 0..7 (wave-uniform)
            int tile = tid & 127;
            bool active = tile < 120;
            int tr = active ? tile / 15 : 0;
            int tc = active ? tile % 15 : 0;
            int s0 = tr * 8, t0 = tc * 4;
            int c = cg0 * 8 + csub;
            int c_s = __builtin_amdgcn_readfirstlane(c);
            const float* Wc = W + c_s * 64;
            float acc[8][4];
#pragma unroll
            for (int r = 0; r < 8; ++r)
#pragma unroll
                for (int cc = 0; cc < 4; ++cc) acc[r][cc] = 0.f;
#pragma unroll
            for (int rho = 0; rho < 15; ++rho) {
                float rb[12];
                const float* rp = &u.c.Rs[(s0 + rho) * 72 + t0];
                *(float4*)&rb[0] = *(const float4*)rp;
                *(float4*)&rb[4] = *(const float4*)(rp + 4);
                *(float4*)&rb[8] = *(const float4*)(rp + 8);
#pragma unroll
                for (int r = 0; r < 8; ++r) {
                    const int p = rho - r;
                    if (p >= 0 && p < 8) {
#pragma unroll
                        for (int q = 0; q < 8; ++q) {
                            float wv = Wc[q * 8 + p];
#pragma unroll
                            for (int cc = 0; cc < 4; ++cc)
                                acc[r][cc] = fmaf(rb[cc + q], wv, acc[r][cc]);
                        }
                    }
                }
            }
            if (active) {
                float* go = g + (size_t)(b * NCH + c) * OHW;
#pragma unroll
                for (int r = 0; r < 8; ++r) {
                    int s = s0 + r;
                    if (s < OH) {
#pragma unroll
                        for (int cc = 0; cc < 4; ++cc) {
                            int tt = t0 + cc;
                            if (tt < OH) {
                                float v = acc[r][cc];
                                go[s * OH + tt] = v;
                                uint32_t bits = __float_as_uint(v) & 0x7fffffffu;
                                atomicAdd(&u.c.hl[bits >> HSHIFT], 1u);
                            }
                        }
                    }
                }
            }
            __syncthreads();
            for (int i = tid; i < NBUCK; i += NTHR) {
                uint32_t v = u.c.hl[i];
                if (v) atomicAdd(&hist[b * NBUCK + i], v);
            }
            __syncthreads();
        }
        grid.sync();

        // ===== phase 3: per-sample bucket threshold (blocks 0..31)
        if (blk < NB) {
            int b = blk;
            uint32_t h[32]; uint32_t s = 0;
            if (tid < 256) {
                const uint32_t* hb = hist + b * NBUCK + tid * 32;
#pragma unroll
                for (int k = 0; k < 32; ++k) { h[k] = hb[k]; s += h[k]; }
                u.t.buf[0][tid] = s;
            }
            __syncthreads();
            int cur = 0;
            for (int d = 1; d < 256; d <<= 1) {
                if (tid < 256) {
                    uint32_t v = u.t.buf[cur][tid];
                    if (tid + d < 256) v += u.t.buf[cur][tid + d];
                    u.t.buf[cur ^ 1][tid] = v;
                }
                cur ^= 1;
                __syncthreads();
            }
            if (tid < 256) {
                uint32_t sufme = u.t.buf[cur][tid];
                uint32_t base  = (tid < 255) ? u.t.buf[cur][tid + 1] : 0u;
                if (tid == 0 && u.t.buf[cur][0] < TGT) thr[b] = 0u;
                if (base < TGT && sufme >= TGT) {
                    uint32_t acc2 = base; int bk = 0;
#pragma unroll
                    for (int k = 31; k >= 0; --k) {
                        acc2 += h[k];
                        if (acc2 >= TGT) { bk = tid * 32 + k; break; }
                    }
                    thr[b] = (uint32_t)bk << HSHIFT;
                }
            }
        }
        grid.sync();

        // ===== phase 4: collect — flat grid-stride over NB*CHW/4 float4
        {
            int slice = blk & (NS - 1);
            const int per_b = CHW / 4;
            for (int gi = blk * NTHR + tid; gi < NB * per_b; gi += NBLK * NTHR) {
                int b = gi / per_b;
                int i4 = gi - b * per_b;
                uint32_t tb = thr[b];
                float4 v4 = ((const float4*)(g + (size_t)b * CHW))[i4];
                float vv[4] = { v4.x, v4.y, v4.z, v4.w };
#pragma unroll
                for (int k = 0; k < 4; ++k) {
                    uint32_t bits = __float_as_uint(vv[k]) & 0x7fffffffu;
                    if (bits >= tb) {
                        int pos = atomicAdd(&cand_cnt[b * NS + slice], 1);
                        if (pos < SCAP) {
                            cand_idx[(b * NS + slice) * SCAP + pos] = (uint32_t)(i4 * 4 + k);
                            cand_g[(b * NS + slice) * SCAP + pos] = vv[k];
                        }
                    }
                }
            }
        }
        grid.sync();

        // ===== phase 5: pool build (blocks 0..31)
        if (blk < NB) {
            int b = blk;
            int n = (t > 0) ? KTOP : 0;
            for (int i = tid; i < BMW / 4; i += NTHR) ((uint4*)u.s.bm)[i] = make_uint4(0u, 0u, 0u, 0u);
            if (tid < NS) cnts[tid] = min(cand_cnt[b * NS + tid], SCAP);
            if (tid == 0) nns_sh = 0;
            __syncthreads();
            if (tid < KTOP) {
                if (tid < n) {
                    uint32_t idx = support_idx[b * KTOP + tid];
                    atomicOr(&u.s.bm[idx >> 5], 1u << (idx & 31));
                    float gv = g[(size_t)b * CHW + idx];
                    sup_g[b * KTOP + tid] = gv;
                    int c = idx / OHW, r = idx % OHW, s = r / OH, tt = r % OH;
                    sup_pk[b * KTOP + tid] = (uint32_t)((c << 12) | (s << 6) | tt);
                } else {
                    sup_g[b * KTOP + tid] = 0.f;
                    sup_pk[b * KTOP + tid] = 0u;
                }
            }
            __syncthreads();
            for (int t0i = tid; t0i < NS * SCAP; t0i += NTHR) {
                int s = t0i >> 9, j = t0i & (SCAP - 1);
                bool keep = false; uint32_t idx = 0; float gv = 0.f;
                if (j < cnts[s]) {
                    idx = cand_idx[(b * NS + s) * SCAP + j];
                    gv = cand_g[(b * NS + s) * SCAP + j];
                    keep = ((u.s.bm[idx >> 5] >> (idx & 31)) & 1u) == 0u;
                }
                ull mk = __ballot(keep);
                if (mk) {
                    int basep = 0;
                    if (lane == 0) basep = atomicAdd(&nns_sh, (int)__popcll(mk));
                    basep = __shfl(basep, 0, 64);
                    if (keep) {
                        int p = basep + (int)__popcll(mk & ((1ull << lane) - 1ull));
                        if (p < NCAP) {
                            u.s.ck[p] = ((ull)(__float_as_uint(gv) & 0x7fffffffu) << 32) | (ull)(uint32_t)(~idx);
                            u.s.cg_l[p] = gv;
                        }
                    }
                }
            }
            __syncthreads();
            int nns = min(nns_sh, NCAP);
            int nns8 = (nns + 7) & ~7;
            for (int i = nns + tid; i < nns8; i += NTHR) u.s.ck[i] = 0ull;
            __syncthreads();
            ull myk[2]; int myr[2];
#pragma unroll
            for (int q = 0; q < 2; ++q) { int i = tid + NTHR * q; myk[q] = (i < nns) ? u.s.ck[i] : 0ull; myr[q] = 0; }
            for (int j = 0; j < nns8; j += 8) {
                ull t0 = u.s.ck[j], t1 = u.s.ck[j+1], t2 = u.s.ck[j+2], t3 = u.s.ck[j+3];
                ull t4 = u.s.ck[j+4], t5 = u.s.ck[j+5], t6 = u.s.ck[j+6], t7 = u.s.ck[j+7];
#pragma unroll
                for (int q = 0; q < 2; ++q) {
                    myr[q] += ((t0 > myk[q]) ? 1 : 0) + ((t1 > myk[q]) ? 1 : 0)
                            + ((t2 > myk[q]) ? 1 : 0) + ((t3 > myk[q]) ? 1 : 0)
                            + ((t4 > myk[q]) ? 1 : 0) + ((t5 > myk[q]) ? 1 : 0)
                            + ((t6 > myk[q]) ? 1 : 0) + ((t7 > myk[q]) ? 1 : 0);
                }
            }
#pragma unroll
            for (int q = 0; q < 2; ++q) {
                int i = tid + NTHR * q;
                if (i < nns && myr[q] < KTOP) {
                    uint32_t idx = ~(uint32_t)myk[q];
                    int r = myr[q];
                    ns_idx[b * KTOP + r] = idx;
                    ns_g[b * KTOP + r] = u.s.cg_l[i];
                    int c = idx / OHW, rr = idx % OHW, s = rr / OH, tt = rr % OH;
                    ns_pk[b * KTOP + r] = (uint32_t)((c << 12) | (s << 6) | tt);
                }
            }
        }
        grid.sync();

        // ===== phase 6: attempts — 544 (a,b) units over 256 blocks; W staged once
        for (int i = tid; i < (NCH * 64) / 4; i += NTHR)
            ((float4*)u.a.Wlds)[i] = ((const float4*)W)[i];
        {
            int n = (t > 0) ? KTOP : 0;
            for (int unit = blk; unit < NATT * NB; unit += NBLK) {
                int a = unit % NATT, b = unit / NATT;
                float alpha = ldexpf(1.f, -a);
                __syncthreads();   // prev unit done (also covers W staging)
                uint32_t nsi = 0, pk_ns = 0, spi = 0, pk_sup = 0;
                float v_ns = 0.f, v_sup = 0.f;
                ull k_ns = 0, k_sup = 0;
                if (tid < KTOP) {
                    nsi = ns_idx[b * KTOP + tid];
                    v_ns = alpha * ns_g[b * KTOP + tid];
                    pk_ns = ns_pk[b * KTOP + tid];
                    k_ns = ((ull)(__float_as_uint(v_ns) & 0x7fffffffu) << 32) | (ull)(uint32_t)(~nsi);
                    u.a.kA[tid] = k_ns;
                    if (tid < n) {
                        spi = support_idx[b * KTOP + tid];
                        v_sup = fmaf(alpha, sup_g[b * KTOP + tid], support_val[b * KTOP + tid]);
                        pk_sup = sup_pk[b * KTOP + tid];
                    } else {
                        spi = (uint32_t)(CHW + tid);  // dummy: unique idx, |v|=0 -> never selected
                        v_sup = 0.f; pk_sup = 0u;
                    }
                    k_sup = ((ull)(__float_as_uint(v_sup) & 0x7fffffffu) << 32) | (ull)(uint32_t)(~spi);
                    u.a.kB[tid] = k_sup;
                } else {
                    for (int i = tid - 256; i < 64 * RSTRIDE; i += 768) u.a.recon[i] = 0.f;
                }
                __syncthreads();
                if (tid < KTOP) {
                    int cb_ns = 0, cb_sup = 0;
                    for (int j = 0; j < KTOP; j += 8) {
                        ull t0 = u.a.kB[j], t1 = u.a.kB[j+1], t2 = u.a.kB[j+2], t3 = u.a.kB[j+3];
                        ull t4 = u.a.kB[j+4], t5 = u.a.kB[j+5], t6 = u.a.kB[j+6], t7 = u.a.kB[j+7];
                        cb_ns  += ((t0 > k_ns) ? 1 : 0) + ((t1 > k_ns) ? 1 : 0)
                                + ((t2 > k_ns) ? 1 : 0) + ((t3 > k_ns) ? 1 : 0)
                                + ((t4 > k_ns) ? 1 : 0) + ((t5 > k_ns) ? 1 : 0)
                                + ((t6 > k_ns) ? 1 : 0) + ((t7 > k_ns) ? 1 : 0);
                        cb_sup += ((t0 > k_sup) ? 1 : 0) + ((t1 > k_sup) ? 1 : 0)
                                + ((t2 > k_sup) ? 1 : 0) + ((t3 > k_sup) ? 1 : 0)
                                + ((t4 > k_sup) ? 1 : 0) + ((t5 > k_sup) ? 1 : 0)
                                + ((t6 > k_sup) ? 1 : 0) + ((t7 > k_sup) ? 1 : 0);
                    }
                    int rank_ns = tid + cb_ns;
                    int lo = 0, hi = KTOP;
                    while (lo < hi) { int mid = (lo + hi) >> 1; if (u.a.kA[mid] > k_sup) lo = mid + 1; else hi = mid; }
                    int rank_sup = lo + cb_sup;
                    size_t o = ((size_t)a * NB + b) * KTOP;
                    if (rank_ns < KTOP) {
                        u.a.s_v[rank_ns] = v_ns; u.a.s_pk[rank_ns] = pk_ns;
                        sel_idx[o + rank_ns] = nsi; sel_val[o + rank_ns] = v_ns;
                    }
                    if (rank_sup < KTOP) {
                        u.a.s_v[rank_sup] = v_sup; u.a.s_pk[rank_sup] = pk_sup;
                        sel_idx[o + rank_sup] = spi; sel_val[o + rank_sup] = v_sup;
                    }
                }
                __syncthreads();
                for (int task = tid; task < KTOP * 64; task += NTHR) {
                    int i = task >> 6, tap = task & 63, p = tap >> 3, q = tap & 7;
                    uint32_t pk = u.a.s_pk[i];
                    float val = u.a.s_v[i];
                    int c = pk >> 12, s = (pk >> 6) & 63, tt = pk & 63;
                    atomicAdd(&u.a.recon[(s + p) * RSTRIDE + (tt + q)], val * u.a.Wlds[c * 64 + tap]);
                }
                __syncthreads();
                float4 y4 = ((const float4*)(Y + b * IMG2))[tid];
                int row = tid >> 4, col = (tid & 15) * 4;
                const float* rr = &u.a.recon[row * RSTRIDE + col];
                double accd = 0.0;
                float d0 = y4.x - rr[0]; accd += (double)d0 * (double)d0;
                float d1 = y4.y - rr[1]; accd += (double)d1 * (double)d1;
                float d2 = y4.z - rr[2]; accd += (double)d2 * (double)d2;
                float d3 = y4.w - rr[3]; accd += (double)d3 * (double)d3;
                for (int d = 32; d > 0; d >>= 1) accd += __shfl_xor(accd, d, 64);
                if (lane == 0) redd[wid] = accd;
                __syncthreads();
                if (tid == 0) {
                    double e = 0.0;
#pragma unroll
                    for (int w2 = 0; w2 < 16; ++w2) e += redd[w2];
                    errg[a * NB + b] = e;
                }
            }
        }
        // loop-top grid.sync() covers att -> next round
    }

    grid.sync();
    // ===== final: zero out (= g buffer) grid-wide
    for (int gi = blk * NTHR + tid; gi < NB * CHW / 4; gi += NBLK * NTHR)
        ((float4*)g)[gi] = make_float4(0.f, 0.f, 0.f, 0.f);
    grid.sync();
    // ===== final: replay round-2 selection + scatter
    if (blk < NB) {
        int b = blk;
        if (tid < NATT) {
            double e = 0.0;
            for (int b2 = 0; b2 < NB; ++b2) e += errg[tid * NB + b2];
            esum[tid] = e;
        } else if (tid == NATT) {
            double l2 = 0.0;
            for (int b2 = 0; b2 < NB; ++b2) l2 += l2buf[b2];   // round 2 wrote l2buf+0
            esum[NATT] = l2;
        }
        __syncthreads();
        if (tid == 0) {
            double l2 = esum[NATT];
            int sel = NATT - 1;
            for (int a2 = 0; a2 < NATT; ++a2) if (esum[a2] < l2) { sel = a2; break; }
            sel_sh = sel;
        }
        __syncthreads();
        int a = sel_sh;
        if (tid < KTOP) {
            size_t o = ((size_t)a * NB + b) * KTOP + tid;
            g[(size_t)b * CHW + sel_idx[o]] = sel_val[o];
        }
    }
}

// ---------------- host ----------------
static size_t align256(size_t x) { return (x + 255) & ~(size_t)255; }

extern "C" void kernel_launch(void* const* d_in, const int* in_sizes, int n_in,
                              void* d_out, int out_size, void* d_ws, size_t ws_size,
                              hipStream_t stream)
{
    const float* Y = (const float*)d_in[0];   // (32,1,64,64)
    const float* W = (const float*)d_in[1];   // (128,1,8,8), normalized
    float* out = (float*)d_out;               // (32,128,57,57) — doubles as dense g

    char* p = (char*)d_ws;
    size_t off = 0;
    auto carve = [&](size_t bytes) { void* r = p + off; off = align256(off + bytes); return r; };
    float*    Rg          = (float*)   carve(NB * IMG2 * sizeof(float));
    uint32_t* hist        = (uint32_t*)carve((size_t)NB * NBUCK * sizeof(uint32_t));
    uint32_t* thr         = (uint32_t*)carve(NB * sizeof(uint32_t));
    int*      cand_cnt    = (int*)     carve(NB * NS * sizeof(int));
    double*   l2buf       = (double*)  carve(2 * NB * sizeof(double));
    double*   err         = (double*)  carve(NATT * NB * sizeof(double));
    uint32_t* support_idx = (uint32_t*)carve(NB * KTOP * sizeof(uint32_t));
    float*    support_val = (float*)   carve(NB * KTOP * sizeof(float));
    uint32_t* sel_idx     = (uint32_t*)carve((size_t)NATT * NB * KTOP * sizeof(uint32_t));
    float*    sel_val     = (float*)   carve((size_t)NATT * NB * KTOP * sizeof(float));
    uint32_t* cand_idx    = (uint32_t*)carve((size_t)NB * NS * SCAP * sizeof(uint32_t));
    float*    cand_g      = (float*)   carve((size_t)NB * NS * SCAP * sizeof(float));
    uint32_t* ns_idx      = (uint32_t*)carve(NB * KTOP * sizeof(uint32_t));
    float*    ns_gbuf     = (float*)   carve(NB * KTOP * sizeof(float));
    uint32_t* ns_pk       = (uint32_t*)carve(NB * KTOP * sizeof(uint32_t));
    float*    sup_gbuf    = (float*)   carve(NB * KTOP * sizeof(float));
    uint32_t* sup_pk      = (uint32_t*)carve(NB * KTOP * sizeof(uint32_t));
    (void)ws_size; (void)in_sizes; (void)n_in; (void)out_size;

    void* args[] = {
        (void*)&Y, (void*)&W, (void*)&out, (void*)&Rg, (void*)&hist, (void*)&thr,
        (void*)&cand_cnt, (void*)&cand_idx, (void*)&cand_g,
        (void*)&ns_idx, (void*)&ns_gbuf, (void*)&ns_pk, (void*)&sup_gbuf, (void*)&sup_pk,
        (void*)&support_idx, (void*)&support_val, (void*)&sel_idx, (void*)&sel_val,
        (void*)&err, (void*)&l2buf
    };
    hipLaunchCooperativeKernel((const void*)k_mega, dim3(NBLK), dim3(NTHR), args, 0, stream);
}